// Round 9
// baseline (457.329 us; speedup 1.0000x reference)
//
#include <hip/hip_runtime.h>

typedef unsigned short u16;
typedef unsigned long long u64;
typedef short bf16x8 __attribute__((ext_vector_type(8)));
typedef float f32x4 __attribute__((ext_vector_type(4)));

__device__ __forceinline__ u16 f2bf(float f) {
  union { float f; unsigned u; } v; v.f = f;
  unsigned r = v.u + 0x7fffu + ((v.u >> 16) & 1u);
  return (u16)(r >> 16);
}

__device__ __forceinline__ float bf2f(u16 b) {
  union { unsigned u; float f; } v; v.u = ((unsigned)b) << 16;
  return v.f;
}

__device__ __forceinline__ u64 pack4(float x, float y, float z, float w) {
  return (u64)f2bf(x) | ((u64)f2bf(y) << 16) |
         ((u64)f2bf(z) << 32) | ((u64)f2bf(w) << 48);
}

// raw hardware exp2/rcp (identical result to ocml path for normal-range
// inputs; scores here are |x| < ~30 so always normal).
__device__ __forceinline__ float fexp2(float x) {
  float r; asm("v_exp_f32 %0, %1" : "=v"(r) : "v"(x)); return r;
}
__device__ __forceinline__ float frcp(float x) {
  float r; asm("v_rcp_f32 %0, %1" : "=v"(r) : "v"(x)); return r;
}

__device__ __forceinline__ void gld_lds16(const u16* g, u16* l) {
  __builtin_amdgcn_global_load_lds(
      (const __attribute__((address_space(1))) void*)g,
      (__attribute__((address_space(3))) void*)l, 16, 0, 0);
}

// attention score scale, folded into Q at qkv-GEMM epilogue:
// exp2(s * 1/sqrt(32) * log2(e)) with Q pre-scaled => exp2(s_raw).
#define QSCALE (0.17677669529663687f * 1.44269504088896340f)

// ===========================================================================
// XCD row-partition convention (R7/R8, measured -27us): XCD x owns rows
// [x*4096,(x+1)*4096). Every kernel remaps blockIdx so blocks on XCD x
// touch exactly that row range -> producer rows stay in local L2 for the
// next kernel's consumers.
// ===========================================================================

// ---------------------------------------------------------------------------
// B^T GEMM: 128x128 tile, BK=64, both-sides chunk swizzle, chunked XCD
// block swizzle. R9: MFMA operand order SWAPPED (mfma(b,a,acc)) so the
// output mapping matches gemm_ln's verified pattern: row=wm+i*16+l16,
// col=wn+j*16+quad*4+r -> each lane holds 4 consecutive cols of one row,
// epilogue packs them into ONE u64 store. 16 dense 512B store-instrs per
// wave instead of 64 scattered 2B-per-lane stores (the old epilogue's
// store-issue + write-drain was the block critical-path tail).
// MODE 0: outb = bf16(acc+bias)
// MODE 1: outb = bf16((acc+bias) * (col<256 ? QSCALE : 1))   (qkv: prescale Q)
// MODE 3: outb = bf16(relu(acc+bias))                        (ffn1)
// ---------------------------------------------------------------------------
template<int MODE>
__global__ __launch_bounds__(256) void gemm_bt(
    const u16* __restrict__ A, const u16* __restrict__ B,
    const float* __restrict__ bias,
    u16* __restrict__ outb,
    int N, int K)
{
  __shared__ u16 As[128 * 64];
  __shared__ u16 Bs[128 * 64];
  const int tid = threadIdx.x;
  const int wave = tid >> 6, lane = tid & 63;
  const int quad = lane >> 4, l16 = lane & 15;

  const int nwg = gridDim.x * gridDim.y;
  int bid = blockIdx.y * gridDim.x + blockIdx.x;
  bid = (bid & 7) * (nwg >> 3) + (bid >> 3);
  const int by = bid / gridDim.x;
  const int bx = bid - by * gridDim.x;
  const int m0 = by * 128, n0 = bx * 128;

  const int wm = (wave >> 1) * 64, wn = (wave & 1) * 64;

  // staging geometry: 32 rows x 8 chunks (16B) per pass, 4 passes = 128 rows
  const int r0 = tid >> 3, ch0 = tid & 7;
  const int sc = ((ch0 ^ (r0 & 7)) * 8);   // pre-swizzled source col (elems)

  const f32x4 zero = {0.f, 0.f, 0.f, 0.f};
  f32x4 acc[4][4];
#pragma unroll
  for (int i = 0; i < 4; i++)
#pragma unroll
    for (int j = 0; j < 4; j++) acc[i][j] = zero;

  const u16* Ap = A + (size_t)(m0 + r0) * K + sc;
  const u16* Bp = B + (size_t)(n0 + r0) * K + sc;
  u16* Asd = &As[tid * 8];
  u16* Bsd = &Bs[tid * 8];

  const int swz = (l16 & 7);  // fragment-read swizzle (row&7 == l16&7)

  for (int kt = 0; kt < K; kt += 64) {
#pragma unroll
    for (int p = 0; p < 4; p++) {
      gld_lds16(Ap + (size_t)(p * 32) * K + kt, Asd + p * 2048);
      gld_lds16(Bp + (size_t)(p * 32) * K + kt, Bsd + p * 2048);
    }
    __syncthreads();
#pragma unroll
    for (int kk = 0; kk < 2; kk++) {
      const int co = ((kk * 4 + quad) ^ swz) * 8;
      bf16x8 a[4], b[4];
#pragma unroll
      for (int i = 0; i < 4; i++)
        a[i] = *(const bf16x8*)&As[(wm + i * 16 + l16) * 64 + co];
#pragma unroll
      for (int j = 0; j < 4; j++)
        b[j] = *(const bf16x8*)&Bs[(wn + j * 16 + l16) * 64 + co];
#pragma unroll
      for (int i = 0; i < 4; i++)
#pragma unroll
        for (int j = 0; j < 4; j++)
          acc[i][j] = __builtin_amdgcn_mfma_f32_16x16x32_bf16(b[j], a[i], acc[i][j], 0, 0, 0);
    }
    __syncthreads();
  }

  // ---- epilogue: row = m0+wm+i*16+l16, cols = n0+wn+j*16+quad*4..+3 ----
#pragma unroll
  for (int i = 0; i < 4; i++) {
    const size_t ro = (size_t)(m0 + wm + i * 16 + l16) * N + n0 + wn;
#pragma unroll
    for (int j = 0; j < 4; j++) {
      float4 bv = *(const float4*)(bias + n0 + wn + j * 16 + quad * 4);
      float v0 = acc[i][j][0] + bv.x;
      float v1 = acc[i][j][1] + bv.y;
      float v2 = acc[i][j][2] + bv.z;
      float v3 = acc[i][j][3] + bv.w;
      if (MODE == 1) {
        if (n0 + wn + j * 16 < 256) {   // Q columns (uniform per 16-block)
          v0 *= QSCALE; v1 *= QSCALE; v2 *= QSCALE; v3 *= QSCALE;
        }
      } else if (MODE == 3) {
        v0 = v0 > 0.f ? v0 : 0.f; v1 = v1 > 0.f ? v1 : 0.f;
        v2 = v2 > 0.f ? v2 : 0.f; v3 = v3 > 0.f ? v3 : 0.f;
      }
      *(u64*)(outb + ro + j * 16 + quad * 4) = pack4(v0, v1, v2, v3);
    }
  }
}

// ---------------------------------------------------------------------------
// Fused GEMM + residual + LayerNorm, N fixed at 256, K compile-time.
// R4-exact core + XCD row-partition remap (R8, measured win). 16x256 wave
// strips, BK=64, both-sides chunk swizzle, single-buffered.
// FINAL=0: outb = bf16( LN(acc+bias+res)*g1+b1 )
// FINAL=1: outf = LN( LN(acc+bias+res)*g1+b1 )*g2+b2  (fp32 d_out)
// ---------------------------------------------------------------------------
template<int FINAL, int KK>
__global__ __launch_bounds__(256) void gemm_ln(
    const u16* __restrict__ A, const u16* __restrict__ B,
    const float* __restrict__ bias, const u16* __restrict__ resb,
    const float* __restrict__ g1, const float* __restrict__ b1,
    const float* __restrict__ g2, const float* __restrict__ b2,
    float* __restrict__ outf, u16* __restrict__ outb)
{
  __shared__ u16 As[64 * 64];        // activation rows (8 KB)
  __shared__ u16 Bs[256 * 64];       // weight rows = output cols (32 KB)
  __shared__ float Pp[FINAL ? 5 * 256 : 3 * 256];  // bias,g1,b1[,g2,b2]

  const int tid = threadIdx.x;
  const int wave = tid >> 6, lane = tid & 63;
  const int quad = lane >> 4, l16 = lane & 15;

  int bid = blockIdx.x;
  bid = (bid & 7) * (gridDim.x >> 3) + (bid >> 3);   // XCD row partition
  const int m0 = bid * 64;

  {
    Pp[tid] = bias[tid];
    Pp[256 + tid] = g1[tid];
    Pp[512 + tid] = b1[tid];
    if (FINAL) {
      Pp[768 + tid] = g2[tid];
      Pp[1024 + tid] = b2[tid];
    }
  }

  const f32x4 zero = {0.f, 0.f, 0.f, 0.f};
  f32x4 acc[16];
#pragma unroll
  for (int j = 0; j < 16; j++) acc[j] = zero;

  // staging: 32 rows x 8 chunks (16B) per pass; As = 2 passes, Bs = 8 passes
  const int r0 = tid >> 3, ch0 = tid & 7;
  const int sc = ((ch0 ^ (r0 & 7)) * 8);
  const u16* Ap = A + (size_t)(m0 + r0) * KK + sc;
  const u16* Bp = B + (size_t)r0 * KK + sc;
  u16* Asd = &As[tid * 8];
  u16* Bsd = &Bs[tid * 8];
  const int swz = (l16 & 7);

  for (int kt = 0; kt < KK; kt += 64) {
#pragma unroll
    for (int p = 0; p < 2; p++)
      gld_lds16(Ap + (size_t)(p * 32) * KK + kt, Asd + p * 2048);
#pragma unroll
    for (int p = 0; p < 8; p++)
      gld_lds16(Bp + (size_t)(p * 32) * KK + kt, Bsd + p * 2048);
    __syncthreads();
#pragma unroll
    for (int kk = 0; kk < 2; kk++) {
      const int co = ((kk * 4 + quad) ^ swz) * 8;
      bf16x8 af = *(const bf16x8*)&As[(wave * 16 + l16) * 64 + co];
#pragma unroll
      for (int j = 0; j < 16; j++) {
        bf16x8 wf = *(const bf16x8*)&Bs[(j * 16 + l16) * 64 + co];
        acc[j] = __builtin_amdgcn_mfma_f32_16x16x32_bf16(wf, af, acc[j], 0, 0, 0);
      }
    }
    __syncthreads();
  }

  // ---- epilogue: v = acc + bias + bf2f(res); LN over the row (l16) ----
  const int row = m0 + wave * 16 + l16;
  const int c4 = quad * 4;  // this lane's 4-col group offset within each j
  float s = 0.f, q = 0.f;
#pragma unroll
  for (int j = 0; j < 16; j++) {
    ushort4 rv = *(const ushort4*)(resb + (size_t)row * 256 + j * 16 + c4);
    float4 bv = *(const float4*)(Pp + j * 16 + c4);
    acc[j][0] += bv.x + bf2f(rv.x);
    acc[j][1] += bv.y + bf2f(rv.y);
    acc[j][2] += bv.z + bf2f(rv.z);
    acc[j][3] += bv.w + bf2f(rv.w);
    s += (acc[j][0] + acc[j][1]) + (acc[j][2] + acc[j][3]);
    q += (acc[j][0] * acc[j][0] + acc[j][1] * acc[j][1]) +
         (acc[j][2] * acc[j][2] + acc[j][3] * acc[j][3]);
  }
  s += __shfl_xor(s, 16, 64); s += __shfl_xor(s, 32, 64);
  q += __shfl_xor(q, 16, 64); q += __shfl_xor(q, 32, 64);
  float mu = s * 0.00390625f;
  float rs = rsqrtf(q * 0.00390625f - mu * mu + 1e-5f);

  if (FINAL == 0) {
#pragma unroll
    for (int j = 0; j < 16; j++) {
      float4 gv = *(const float4*)(Pp + 256 + j * 16 + c4);
      float4 bv = *(const float4*)(Pp + 512 + j * 16 + c4);
      float4 y;
      y.x = (acc[j][0] - mu) * rs * gv.x + bv.x;
      y.y = (acc[j][1] - mu) * rs * gv.y + bv.y;
      y.z = (acc[j][2] - mu) * rs * gv.z + bv.z;
      y.w = (acc[j][3] - mu) * rs * gv.w + bv.w;
      const size_t off = (size_t)row * 256 + j * 16 + c4;
      *(u64*)(outb + off) = pack4(y.x, y.y, y.z, y.w);
    }
  } else {
    // y = LN1(v)*g1+b1 in place, then second LN over y
    float s2 = 0.f, q2 = 0.f;
#pragma unroll
    for (int j = 0; j < 16; j++) {
      float4 gv = *(const float4*)(Pp + 256 + j * 16 + c4);
      float4 bv = *(const float4*)(Pp + 512 + j * 16 + c4);
      acc[j][0] = (acc[j][0] - mu) * rs * gv.x + bv.x;
      acc[j][1] = (acc[j][1] - mu) * rs * gv.y + bv.y;
      acc[j][2] = (acc[j][2] - mu) * rs * gv.z + bv.z;
      acc[j][3] = (acc[j][3] - mu) * rs * gv.w + bv.w;
      s2 += (acc[j][0] + acc[j][1]) + (acc[j][2] + acc[j][3]);
      q2 += (acc[j][0] * acc[j][0] + acc[j][1] * acc[j][1]) +
            (acc[j][2] * acc[j][2] + acc[j][3] * acc[j][3]);
    }
    s2 += __shfl_xor(s2, 16, 64); s2 += __shfl_xor(s2, 32, 64);
    q2 += __shfl_xor(q2, 16, 64); q2 += __shfl_xor(q2, 32, 64);
    float mu2 = s2 * 0.00390625f;
    float rs2 = rsqrtf(q2 * 0.00390625f - mu2 * mu2 + 1e-5f);
#pragma unroll
    for (int j = 0; j < 16; j++) {
      float4 gv = *(const float4*)(Pp + 768 + j * 16 + c4);
      float4 bv = *(const float4*)(Pp + 1024 + j * 16 + c4);
      float4 z;
      z.x = (acc[j][0] - mu2) * rs2 * gv.x + bv.x;
      z.y = (acc[j][1] - mu2) * rs2 * gv.y + bv.y;
      z.z = (acc[j][2] - mu2) * rs2 * gv.z + bv.z;
      z.w = (acc[j][3] - mu2) * rs2 * gv.w + bv.w;
      *(float4*)(outf + (size_t)row * 256 + j * 16 + c4) = z;
    }
  }
}

// ---------------------------------------------------------------------------
// Attention v11 (unchanged from R8, measured): XCD remap, NO-MAX softmax,
// Q pre-scaled at qkv GEMM, raw v_exp_f32, lsum via ones-row MFMA,
// setprio around MFMA clusters, Q prefetch across qc.
// ---------------------------------------------------------------------------
__global__ __launch_bounds__(256) void attn_k(
    const u16* __restrict__ qkv, u16* __restrict__ ob)
{
  __shared__ u16 Ks[256 * 32];       // [key][d] row-major
  __shared__ u16 Vt[32 * 256];       // [d][key] swizzled: chunk^=(d&7)
  __shared__ u16 Pw[4][16 * 64];     // per-wave quarter-P [q][keyloc], swizzled

  const int tid = threadIdx.x;
  const int wave = tid >> 6, lane = tid & 63;
  const int quad = lane >> 4, l16 = lane & 15;

  int bid = blockIdx.x;
  bid = (bid & 7) * (gridDim.x >> 3) + (bid >> 3);   // XCD row partition
  const int g = bid >> 3, h = bid & 7;
  const int node0 = g << 8;
  const int qoff = h * 32, koff = 256 + h * 32, voff = 512 + h * 32;

  {
    const int kr = tid >> 2, kc = (tid & 3) * 8;
    const u16* Kp = qkv + (size_t)(node0 + kr) * 768 + koff + kc;
    u16* Kd = &Ks[tid * 8];
#pragma unroll
    for (int pass = 0; pass < 4; pass++)
      gld_lds16(Kp + (size_t)pass * 64 * 768, Kd + pass * 2048);
  }

  {
    const int d = lane & 31;
    const int kb2 = lane >> 5;
#pragma unroll
    for (int t = 0; t < 4; t++) {
      const int kbg = wave * 8 + t * 2 + kb2;
      u16 vals[8];
#pragma unroll
      for (int i = 0; i < 8; i++)
        vals[i] = qkv[(size_t)(node0 + kbg * 8 + i) * 768 + voff + d];
      *(bf16x8*)&Vt[d * 256 + ((kbg ^ (d & 7)) << 3)] = *(bf16x8*)vals;
    }
  }

  __syncthreads();

  const f32x4 zero = {0.f, 0.f, 0.f, 0.f};
  bf16x8 ones;
#pragma unroll
  for (int i = 0; i < 8; i++) ones[i] = (short)0x3F80;  // bf16(1.0)
  u16* pw = Pw[wave];

  bf16x8 qf = *(const bf16x8*)&qkv[(size_t)(node0 + wave * 16 + l16) * 768 + qoff + quad * 8];

#pragma unroll
  for (int qc = 0; qc < 4; qc++) {
    const int q0 = qc * 64 + wave * 16;

    bf16x8 qnext = qf;
    if (qc < 3)
      qnext = *(const bf16x8*)&qkv[(size_t)(node0 + q0 + 64 + l16) * 768 + qoff + quad * 8];

    f32x4 o[2] = {zero, zero};
    f32x4 ls = zero;   // ones-MFMA row-sum accumulator (all regs equal at end)

#pragma unroll
    for (int half = 0; half < 2; half++) {
      f32x4 s[8];
      __builtin_amdgcn_s_setprio(1);
#pragma unroll
      for (int ib = 0; ib < 8; ib++) {
        bf16x8 kf = *(const bf16x8*)&Ks[(half * 128 + ib * 16 + l16) * 32 + quad * 8];
        s[ib] = __builtin_amdgcn_mfma_f32_16x16x32_bf16(kf, qf, zero, 0, 0, 0);
      }
      __builtin_amdgcn_s_setprio(0);

#pragma unroll
      for (int Q = 0; Q < 2; Q++) {
#pragma unroll
        for (int ib = 0; ib < 4; ib++) {
          f32x4 p;
#pragma unroll
          for (int r = 0; r < 4; r++) p[r] = fexp2(s[Q * 4 + ib][r]);
          union { float f; unsigned u; } u0, u1, u2, u3;
          u0.f = p[0]; u1.f = p[1]; u2.f = p[2]; u3.f = p[3];
          uint2 pk;
          pk.x = __builtin_amdgcn_perm(u1.u, u0.u, 0x07060302u);
          pk.y = __builtin_amdgcn_perm(u3.u, u2.u, 0x07060302u);
          const int c = 2 * ib + (quad >> 1);
          *(uint2*)&pw[l16 * 64 + ((c ^ (l16 & 7)) << 3) + (quad & 1) * 4] = pk;
        }
#pragma unroll
        for (int ks = 0; ks < 2; ks++) {
          bf16x8 pf = *(const bf16x8*)&pw[l16 * 64 + (((ks * 4 + quad) ^ (l16 & 7)) << 3)];
          __builtin_amdgcn_s_setprio(1);
#pragma unroll
          for (int ib2 = 0; ib2 < 2; ib2++) {
            const int d = ib2 * 16 + l16;
            const int chunk = half * 16 + Q * 8 + ks * 4 + quad;
            bf16x8 vf = *(const bf16x8*)&Vt[d * 256 + ((chunk ^ (d & 7)) << 3)];
            o[ib2] = __builtin_amdgcn_mfma_f32_16x16x32_bf16(vf, pf, o[ib2], 0, 0, 0);
          }
          ls = __builtin_amdgcn_mfma_f32_16x16x32_bf16(ones, pf, ls, 0, 0, 0);
          __builtin_amdgcn_s_setprio(0);
        }
      }
    }

    const float inv = frcp(ls[0]);   // every lane holds its query's full sum
    const size_t rowbase = (size_t)(node0 + q0 + l16) * 256 + h * 32;
#pragma unroll
    for (int ib2 = 0; ib2 < 2; ib2++) {
      u64 pk = pack4(o[ib2][0] * inv, o[ib2][1] * inv, o[ib2][2] * inv, o[ib2][3] * inv);
      *(u64*)&ob[rowbase + ib2 * 16 + quad * 4] = pk;
    }
    qf = qnext;
  }
}

// ---------------------------------------------------------------------------
// fp32 -> bf16 convert for x + all weights (segment bounds are compile-time).
// ---------------------------------------------------------------------------
__global__ __launch_bounds__(256) void cvt_k(
    const float* __restrict__ s0, const float* __restrict__ s1,
    const float* __restrict__ s2, const float* __restrict__ s3,
    const float* __restrict__ s4, const float* __restrict__ s5,
    u16* __restrict__ d0, u16* __restrict__ d1, u16* __restrict__ d2,
    u16* __restrict__ d3, u16* __restrict__ d4, u16* __restrict__ d5)
{
  int t = (blockIdx.x * 256 + threadIdx.x) * 4;
  const float* s; u16* d; int off;
  if (t < 4194304)      { s = s0; d = d0; off = t; }
  else if (t < 4227072) { s = s1; d = d1; off = t - 4194304; }
  else if (t < 4816896) { s = s2; d = d2; off = t - 4227072; }
  else if (t < 5013504) { s = s3; d = d3; off = t - 4816896; }
  else if (t < 5406720) { s = s4; d = d4; off = t - 5013504; }
  else                  { s = s5; d = d5; off = t - 5406720; }
  float4 v = *(const float4*)(s + off);
  *(u64*)(d + off) = pack4(v.x, v.y, v.z, v.w);
}

extern "C" void kernel_launch(void* const* d_in, const int* in_sizes, int n_in,
                              void* d_out, int out_size, void* d_ws, size_t ws_size,
                              hipStream_t stream) {
  const float* x     = (const float*)d_in[0];
  const float* Wp    = (const float*)d_in[3];
  const float* bp    = (const float*)d_in[4];
  const float* in_w  = (const float*)d_in[5];
  const float* in_b  = (const float*)d_in[6];
  const float* out_w = (const float*)d_in[7];
  const float* out_b = (const float*)d_in[8];
  const float* n1_g  = (const float*)d_in[9];
  const float* n1_b  = (const float*)d_in[10];
  const float* W1    = (const float*)d_in[11];
  const float* b1    = (const float*)d_in[12];
  const float* W2    = (const float*)d_in[13];
  const float* b2    = (const float*)d_in[14];
  const float* n2_g  = (const float*)d_in[15];
  const float* n2_b  = (const float*)d_in[16];
  const float* ln_g  = (const float*)d_in[17];
  const float* ln_b  = (const float*)d_in[18];
  float* out = (float*)d_out;

  if (ws_size < 100000000u) return;  // fail loudly (out stays poisoned)

  char* ws = (char*)d_ws;
  u16* hb  = (u16*)(ws);                        // [32768,256] bf16 residual master
  u16* ob  = (u16*)(ws + 16777216);             // attention out bf16
  u16* mid = (u16*)(ws + 33554432);             // qkv [N,768] / ffn-mid [N,512]
  u16* wb  = (u16*)(ws + 83886080);             // bf16 weights
  u16* xb  = (u16*)(ws + 87097344);             // bf16 x

  u16* Wpb   = wb;
  u16* inwb  = wb + 32768;
  u16* outwb = wb + 622592;
  u16* W1b   = wb + 819200;
  u16* W2b   = wb + 1212416;

  cvt_k<<<5664, 256, 0, stream>>>(x, Wp, in_w, out_w, W1, W2,
                                  xb, Wpb, inwb, outwb, W1b, W2b);

  // h = x @ Wp^T + bp  -> hb (bf16 master)
  gemm_bt<0><<<dim3(2, 256), 256, 0, stream>>>(xb, Wpb, bp, hb, 256, 128);

  for (int l = 0; l < 3; l++) {
    // qkv (Q columns pre-scaled by QSCALE for attention)
    gemm_bt<1><<<dim3(6, 256), 256, 0, stream>>>(hb, inwb + l * 196608, in_b + l * 768,
                                                 mid, 768, 256);
    // attention
    attn_k<<<1024, 256, 0, stream>>>(mid, ob);
    // out-proj + residual + LN1 -> hb (bf16, self-referencing res is per-row safe)
    gemm_ln<0, 256><<<512, 256, 0, stream>>>(ob, outwb + l * 65536, out_b + l * 256,
                                             hb, n1_g + l * 256, n1_b + l * 256,
                                             nullptr, nullptr, nullptr, hb);
    // FFN1 (relu) -> mid
    gemm_bt<3><<<dim3(4, 256), 256, 0, stream>>>(hb, W1b + l * 131072, b1 + l * 512,
                                                 mid, 512, 256);
    // FFN2 + residual + LN2 (+final LN on last layer)
    if (l < 2) {
      gemm_ln<0, 512><<<512, 256, 0, stream>>>(mid, W2b + l * 131072, b2 + l * 256,
                                               hb, n2_g + l * 256, n2_b + l * 256,
                                               nullptr, nullptr, nullptr, hb);
    } else {
      gemm_ln<1, 512><<<512, 256, 0, stream>>>(mid, W2b + l * 131072, b2 + l * 256,
                                               hb, n2_g + l * 256, n2_b + l * 256,
                                               ln_g, ln_b, out, nullptr);
    }
  }
}

// Round 10
// 414.532 us; speedup vs baseline: 1.1032x; 1.1032x over previous
//
#include <hip/hip_runtime.h>

typedef unsigned short u16;
typedef unsigned long long u64;
typedef short bf16x8 __attribute__((ext_vector_type(8)));
typedef float f32x4 __attribute__((ext_vector_type(4)));

__device__ __forceinline__ u16 f2bf(float f) {
  union { float f; unsigned u; } v; v.f = f;
  unsigned r = v.u + 0x7fffu + ((v.u >> 16) & 1u);
  return (u16)(r >> 16);
}

__device__ __forceinline__ float bf2f(u16 b) {
  union { unsigned u; float f; } v; v.u = ((unsigned)b) << 16;
  return v.f;
}

__device__ __forceinline__ u64 pack4(float x, float y, float z, float w) {
  return (u64)f2bf(x) | ((u64)f2bf(y) << 16) |
         ((u64)f2bf(z) << 32) | ((u64)f2bf(w) << 48);
}

// raw hardware exp2/rcp (identical result to ocml path for normal-range
// inputs; scores here are |x| < ~30 so always normal).
__device__ __forceinline__ float fexp2(float x) {
  float r; asm("v_exp_f32 %0, %1" : "=v"(r) : "v"(x)); return r;
}
__device__ __forceinline__ float frcp(float x) {
  float r; asm("v_rcp_f32 %0, %1" : "=v"(r) : "v"(x)); return r;
}

__device__ __forceinline__ void gld_lds16(const u16* g, u16* l) {
  __builtin_amdgcn_global_load_lds(
      (const __attribute__((address_space(1))) void*)g,
      (__attribute__((address_space(3))) void*)l, 16, 0, 0);
}

// attention score scale, folded into Q at qkv-GEMM epilogue:
// exp2(s * 1/sqrt(32) * log2(e)) with Q pre-scaled => exp2(s_raw).
#define QSCALE (0.17677669529663687f * 1.44269504088896340f)

// ===========================================================================
// XCD row-partition convention (R7/R8, measured -27us): XCD x owns rows
// [x*4096,(x+1)*4096). Every kernel remaps blockIdx so blocks on XCD x
// touch exactly that row range -> producer rows stay in local L2 for the
// next kernel's consumers.
// R9 lesson: packed-u64 epilogue with row-on-l16 REGRESSED gemm_bt (+5us
// each): consecutive lanes 1536B apart -> 16 scattered transactions per
// store instr vs 4; store instruction count was never the bottleneck.
// Keep the scalar col-on-l16 epilogue (R8-measured).
// ===========================================================================

// ---------------------------------------------------------------------------
// B^T GEMM (R8-exact, measured 422.5us config): 128x128 tile, BK=64,
// both-sides chunk swizzle, chunked XCD block swizzle, scalar epilogue.
// MODE 0: outb = bf16(acc+bias)
// MODE 1: outb = bf16((acc+bias) * (col<256 ? QSCALE : 1))   (qkv: prescale Q)
// MODE 3: outb = bf16(relu(acc+bias))                        (ffn1)
// ---------------------------------------------------------------------------
template<int MODE>
__global__ __launch_bounds__(256) void gemm_bt(
    const u16* __restrict__ A, const u16* __restrict__ B,
    const float* __restrict__ bias,
    u16* __restrict__ outb,
    int N, int K)
{
  __shared__ u16 As[128 * 64];
  __shared__ u16 Bs[128 * 64];
  const int tid = threadIdx.x;
  const int wave = tid >> 6, lane = tid & 63;
  const int quad = lane >> 4, l16 = lane & 15;

  const int nwg = gridDim.x * gridDim.y;
  int bid = blockIdx.y * gridDim.x + blockIdx.x;
  bid = (bid & 7) * (nwg >> 3) + (bid >> 3);
  const int by = bid / gridDim.x;
  const int bx = bid - by * gridDim.x;
  const int m0 = by * 128, n0 = bx * 128;

  const int wm = (wave >> 1) * 64, wn = (wave & 1) * 64;

  // staging geometry: 32 rows x 8 chunks (16B) per pass, 4 passes = 128 rows
  const int r0 = tid >> 3, ch0 = tid & 7;
  const int sc = ((ch0 ^ (r0 & 7)) * 8);   // pre-swizzled source col (elems)

  const f32x4 zero = {0.f, 0.f, 0.f, 0.f};
  f32x4 acc[4][4];
#pragma unroll
  for (int i = 0; i < 4; i++)
#pragma unroll
    for (int j = 0; j < 4; j++) acc[i][j] = zero;

  const u16* Ap = A + (size_t)(m0 + r0) * K + sc;
  const u16* Bp = B + (size_t)(n0 + r0) * K + sc;
  u16* Asd = &As[tid * 8];
  u16* Bsd = &Bs[tid * 8];

  const int swz = (l16 & 7);  // fragment-read swizzle (row&7 == l16&7)

  for (int kt = 0; kt < K; kt += 64) {
#pragma unroll
    for (int p = 0; p < 4; p++) {
      gld_lds16(Ap + (size_t)(p * 32) * K + kt, Asd + p * 2048);
      gld_lds16(Bp + (size_t)(p * 32) * K + kt, Bsd + p * 2048);
    }
    __syncthreads();
#pragma unroll
    for (int kk = 0; kk < 2; kk++) {
      const int co = ((kk * 4 + quad) ^ swz) * 8;
      bf16x8 a[4], b[4];
#pragma unroll
      for (int i = 0; i < 4; i++)
        a[i] = *(const bf16x8*)&As[(wm + i * 16 + l16) * 64 + co];
#pragma unroll
      for (int j = 0; j < 4; j++)
        b[j] = *(const bf16x8*)&Bs[(wn + j * 16 + l16) * 64 + co];
#pragma unroll
      for (int i = 0; i < 4; i++)
#pragma unroll
        for (int j = 0; j < 4; j++)
          acc[i][j] = __builtin_amdgcn_mfma_f32_16x16x32_bf16(a[i], b[j], acc[i][j], 0, 0, 0);
    }
    __syncthreads();
  }

  float bj[4];
#pragma unroll
  for (int j = 0; j < 4; j++) bj[j] = bias[n0 + wn + j * 16 + l16];

#pragma unroll
  for (int i = 0; i < 4; i++) {
    const int Rb = m0 + wm + i * 16 + quad * 4;
#pragma unroll
    for (int r = 0; r < 4; r++) {
      const size_t ro = (size_t)(Rb + r) * N;
#pragma unroll
      for (int j = 0; j < 4; j++) {
        const int C = n0 + wn + j * 16 + l16;
        float v = acc[i][j][r] + bj[j];
        if (MODE == 1) {
          if (n0 + wn + j * 16 < 256) v *= QSCALE;  // Q columns (wave-uniform)
          outb[ro + C] = f2bf(v);
        } else if (MODE == 0) {
          outb[ro + C] = f2bf(v);
        } else {
          outb[ro + C] = f2bf(v > 0.f ? v : 0.f);
        }
      }
    }
  }
}

// ---------------------------------------------------------------------------
// proj_k (R10): input projection reading fp32 x DIRECTLY -- removes x from
// cvt_k (72% of its work) and the xb round-trip. A-tile: linear fp32 global
// reads -> f2bf convert in regs (identical rounding to cvt_k) -> swizzled
// ds_write_b64 at pos ch^(row&7) (spreads 8 rows over all banks, and the
// fragment reads' XOR lands on the same layout as the gld_lds16 path).
// B (Wp bf16, cvt'd) stays on the proven gld_lds16 path. Compute + epilogue
// = gemm_bt MODE 0 exact. N=256, K=128 fixed; grid dim3(2,256).
// ---------------------------------------------------------------------------
__global__ __launch_bounds__(256) void proj_k(
    const float* __restrict__ X, const u16* __restrict__ B,
    const float* __restrict__ bias, u16* __restrict__ outb)
{
  __shared__ u16 As[128 * 64];
  __shared__ u16 Bs[128 * 64];
  const int tid = threadIdx.x;
  const int wave = tid >> 6, lane = tid & 63;
  const int quad = lane >> 4, l16 = lane & 15;
  const int N = 256, K = 128;

  const int nwg = gridDim.x * gridDim.y;
  int bid = blockIdx.y * gridDim.x + blockIdx.x;
  bid = (bid & 7) * (nwg >> 3) + (bid >> 3);
  const int by = bid / gridDim.x;
  const int bx = bid - by * gridDim.x;
  const int m0 = by * 128, n0 = bx * 128;

  const int wm = (wave >> 1) * 64, wn = (wave & 1) * 64;

  const int r0 = tid >> 3, ch0 = tid & 7;
  const int sc = ((ch0 ^ (r0 & 7)) * 8);   // B: pre-swizzled source col

  const f32x4 zero = {0.f, 0.f, 0.f, 0.f};
  f32x4 acc[4][4];
#pragma unroll
  for (int i = 0; i < 4; i++)
#pragma unroll
    for (int j = 0; j < 4; j++) acc[i][j] = zero;

  const u16* Bp = B + (size_t)(n0 + r0) * K + sc;
  u16* Bsd = &Bs[tid * 8];
  const int swz = (l16 & 7);

  for (int kt = 0; kt < K; kt += 64) {
#pragma unroll
    for (int p = 0; p < 4; p++)
      gld_lds16(Bp + (size_t)(p * 32) * K + kt, Bsd + p * 2048);
    // A: fp32 -> bf16 reg-staged, linear global read, swizzled LDS write
#pragma unroll
    for (int p = 0; p < 4; p++) {
      const int r = p * 32 + r0;
      const float* src = X + (size_t)(m0 + r) * K + kt + ch0 * 8;
      float4 v0 = *(const float4*)src;
      float4 v1 = *(const float4*)(src + 4);
      const int la = r * 64 + ((ch0 ^ (r0 & 7)) * 8);
      *(u64*)&As[la]     = pack4(v0.x, v0.y, v0.z, v0.w);
      *(u64*)&As[la + 4] = pack4(v1.x, v1.y, v1.z, v1.w);
    }
    __syncthreads();
#pragma unroll
    for (int kk = 0; kk < 2; kk++) {
      const int co = ((kk * 4 + quad) ^ swz) * 8;
      bf16x8 a[4], b[4];
#pragma unroll
      for (int i = 0; i < 4; i++)
        a[i] = *(const bf16x8*)&As[(wm + i * 16 + l16) * 64 + co];
#pragma unroll
      for (int j = 0; j < 4; j++)
        b[j] = *(const bf16x8*)&Bs[(wn + j * 16 + l16) * 64 + co];
#pragma unroll
      for (int i = 0; i < 4; i++)
#pragma unroll
        for (int j = 0; j < 4; j++)
          acc[i][j] = __builtin_amdgcn_mfma_f32_16x16x32_bf16(a[i], b[j], acc[i][j], 0, 0, 0);
    }
    __syncthreads();
  }

  float bj[4];
#pragma unroll
  for (int j = 0; j < 4; j++) bj[j] = bias[n0 + wn + j * 16 + l16];

#pragma unroll
  for (int i = 0; i < 4; i++) {
    const int Rb = m0 + wm + i * 16 + quad * 4;
#pragma unroll
    for (int r = 0; r < 4; r++) {
      const size_t ro = (size_t)(Rb + r) * N;
#pragma unroll
      for (int j = 0; j < 4; j++)
        outb[ro + n0 + wn + j * 16 + l16] = f2bf(acc[i][j][r] + bj[j]);
    }
  }
}

// ---------------------------------------------------------------------------
// Fused GEMM + residual + LayerNorm, N fixed at 256, K compile-time.
// R4-exact core + XCD row-partition remap (R8, measured win). 16x256 wave
// strips, BK=64, both-sides chunk swizzle, single-buffered.
// FINAL=0: outb = bf16( LN(acc+bias+res)*g1+b1 )
// FINAL=1: outf = LN( LN(acc+bias+res)*g1+b1 )*g2+b2  (fp32 d_out)
// ---------------------------------------------------------------------------
template<int FINAL, int KK>
__global__ __launch_bounds__(256) void gemm_ln(
    const u16* __restrict__ A, const u16* __restrict__ B,
    const float* __restrict__ bias, const u16* __restrict__ resb,
    const float* __restrict__ g1, const float* __restrict__ b1,
    const float* __restrict__ g2, const float* __restrict__ b2,
    float* __restrict__ outf, u16* __restrict__ outb)
{
  __shared__ u16 As[64 * 64];        // activation rows (8 KB)
  __shared__ u16 Bs[256 * 64];       // weight rows = output cols (32 KB)
  __shared__ float Pp[FINAL ? 5 * 256 : 3 * 256];  // bias,g1,b1[,g2,b2]

  const int tid = threadIdx.x;
  const int wave = tid >> 6, lane = tid & 63;
  const int quad = lane >> 4, l16 = lane & 15;

  int bid = blockIdx.x;
  bid = (bid & 7) * (gridDim.x >> 3) + (bid >> 3);   // XCD row partition
  const int m0 = bid * 64;

  {
    Pp[tid] = bias[tid];
    Pp[256 + tid] = g1[tid];
    Pp[512 + tid] = b1[tid];
    if (FINAL) {
      Pp[768 + tid] = g2[tid];
      Pp[1024 + tid] = b2[tid];
    }
  }

  const f32x4 zero = {0.f, 0.f, 0.f, 0.f};
  f32x4 acc[16];
#pragma unroll
  for (int j = 0; j < 16; j++) acc[j] = zero;

  // staging: 32 rows x 8 chunks (16B) per pass; As = 2 passes, Bs = 8 passes
  const int r0 = tid >> 3, ch0 = tid & 7;
  const int sc = ((ch0 ^ (r0 & 7)) * 8);
  const u16* Ap = A + (size_t)(m0 + r0) * KK + sc;
  const u16* Bp = B + (size_t)r0 * KK + sc;
  u16* Asd = &As[tid * 8];
  u16* Bsd = &Bs[tid * 8];
  const int swz = (l16 & 7);

  for (int kt = 0; kt < KK; kt += 64) {
#pragma unroll
    for (int p = 0; p < 2; p++)
      gld_lds16(Ap + (size_t)(p * 32) * KK + kt, Asd + p * 2048);
#pragma unroll
    for (int p = 0; p < 8; p++)
      gld_lds16(Bp + (size_t)(p * 32) * KK + kt, Bsd + p * 2048);
    __syncthreads();
#pragma unroll
    for (int kk = 0; kk < 2; kk++) {
      const int co = ((kk * 4 + quad) ^ swz) * 8;
      bf16x8 af = *(const bf16x8*)&As[(wave * 16 + l16) * 64 + co];
#pragma unroll
      for (int j = 0; j < 16; j++) {
        bf16x8 wf = *(const bf16x8*)&Bs[(j * 16 + l16) * 64 + co];
        acc[j] = __builtin_amdgcn_mfma_f32_16x16x32_bf16(wf, af, acc[j], 0, 0, 0);
      }
    }
    __syncthreads();
  }

  // ---- epilogue: v = acc + bias + bf2f(res); LN over the row (l16) ----
  const int row = m0 + wave * 16 + l16;
  const int c4 = quad * 4;  // this lane's 4-col group offset within each j
  float s = 0.f, q = 0.f;
#pragma unroll
  for (int j = 0; j < 16; j++) {
    ushort4 rv = *(const ushort4*)(resb + (size_t)row * 256 + j * 16 + c4);
    float4 bv = *(const float4*)(Pp + j * 16 + c4);
    acc[j][0] += bv.x + bf2f(rv.x);
    acc[j][1] += bv.y + bf2f(rv.y);
    acc[j][2] += bv.z + bf2f(rv.z);
    acc[j][3] += bv.w + bf2f(rv.w);
    s += (acc[j][0] + acc[j][1]) + (acc[j][2] + acc[j][3]);
    q += (acc[j][0] * acc[j][0] + acc[j][1] * acc[j][1]) +
         (acc[j][2] * acc[j][2] + acc[j][3] * acc[j][3]);
  }
  s += __shfl_xor(s, 16, 64); s += __shfl_xor(s, 32, 64);
  q += __shfl_xor(q, 16, 64); q += __shfl_xor(q, 32, 64);
  float mu = s * 0.00390625f;
  float rs = rsqrtf(q * 0.00390625f - mu * mu + 1e-5f);

  if (FINAL == 0) {
#pragma unroll
    for (int j = 0; j < 16; j++) {
      float4 gv = *(const float4*)(Pp + 256 + j * 16 + c4);
      float4 bv = *(const float4*)(Pp + 512 + j * 16 + c4);
      float4 y;
      y.x = (acc[j][0] - mu) * rs * gv.x + bv.x;
      y.y = (acc[j][1] - mu) * rs * gv.y + bv.y;
      y.z = (acc[j][2] - mu) * rs * gv.z + bv.z;
      y.w = (acc[j][3] - mu) * rs * gv.w + bv.w;
      const size_t off = (size_t)row * 256 + j * 16 + c4;
      *(u64*)(outb + off) = pack4(y.x, y.y, y.z, y.w);
    }
  } else {
    // y = LN1(v)*g1+b1 in place, then second LN over y
    float s2 = 0.f, q2 = 0.f;
#pragma unroll
    for (int j = 0; j < 16; j++) {
      float4 gv = *(const float4*)(Pp + 256 + j * 16 + c4);
      float4 bv = *(const float4*)(Pp + 512 + j * 16 + c4);
      acc[j][0] = (acc[j][0] - mu) * rs * gv.x + bv.x;
      acc[j][1] = (acc[j][1] - mu) * rs * gv.y + bv.y;
      acc[j][2] = (acc[j][2] - mu) * rs * gv.z + bv.z;
      acc[j][3] = (acc[j][3] - mu) * rs * gv.w + bv.w;
      s2 += (acc[j][0] + acc[j][1]) + (acc[j][2] + acc[j][3]);
      q2 += (acc[j][0] * acc[j][0] + acc[j][1] * acc[j][1]) +
            (acc[j][2] * acc[j][2] + acc[j][3] * acc[j][3]);
    }
    s2 += __shfl_xor(s2, 16, 64); s2 += __shfl_xor(s2, 32, 64);
    q2 += __shfl_xor(q2, 16, 64); q2 += __shfl_xor(q2, 32, 64);
    float mu2 = s2 * 0.00390625f;
    float rs2 = rsqrtf(q2 * 0.00390625f - mu2 * mu2 + 1e-5f);
#pragma unroll
    for (int j = 0; j < 16; j++) {
      float4 gv = *(const float4*)(Pp + 768 + j * 16 + c4);
      float4 bv = *(const float4*)(Pp + 1024 + j * 16 + c4);
      float4 z;
      z.x = (acc[j][0] - mu2) * rs2 * gv.x + bv.x;
      z.y = (acc[j][1] - mu2) * rs2 * gv.y + bv.y;
      z.z = (acc[j][2] - mu2) * rs2 * gv.z + bv.z;
      z.w = (acc[j][3] - mu2) * rs2 * gv.w + bv.w;
      *(float4*)(outf + (size_t)row * 256 + j * 16 + c4) = z;
    }
  }
}

// ---------------------------------------------------------------------------
// Attention v11 (R8-exact, measured): XCD remap, NO-MAX softmax, Q
// pre-scaled at qkv GEMM, raw v_exp_f32, lsum via ones-row MFMA, setprio
// around MFMA clusters, Q prefetch across qc.
// ---------------------------------------------------------------------------
__global__ __launch_bounds__(256) void attn_k(
    const u16* __restrict__ qkv, u16* __restrict__ ob)
{
  __shared__ u16 Ks[256 * 32];       // [key][d] row-major
  __shared__ u16 Vt[32 * 256];       // [d][key] swizzled: chunk^=(d&7)
  __shared__ u16 Pw[4][16 * 64];     // per-wave quarter-P [q][keyloc], swizzled

  const int tid = threadIdx.x;
  const int wave = tid >> 6, lane = tid & 63;
  const int quad = lane >> 4, l16 = lane & 15;

  int bid = blockIdx.x;
  bid = (bid & 7) * (gridDim.x >> 3) + (bid >> 3);   // XCD row partition
  const int g = bid >> 3, h = bid & 7;
  const int node0 = g << 8;
  const int qoff = h * 32, koff = 256 + h * 32, voff = 512 + h * 32;

  {
    const int kr = tid >> 2, kc = (tid & 3) * 8;
    const u16* Kp = qkv + (size_t)(node0 + kr) * 768 + koff + kc;
    u16* Kd = &Ks[tid * 8];
#pragma unroll
    for (int pass = 0; pass < 4; pass++)
      gld_lds16(Kp + (size_t)pass * 64 * 768, Kd + pass * 2048);
  }

  {
    const int d = lane & 31;
    const int kb2 = lane >> 5;
#pragma unroll
    for (int t = 0; t < 4; t++) {
      const int kbg = wave * 8 + t * 2 + kb2;
      u16 vals[8];
#pragma unroll
      for (int i = 0; i < 8; i++)
        vals[i] = qkv[(size_t)(node0 + kbg * 8 + i) * 768 + voff + d];
      *(bf16x8*)&Vt[d * 256 + ((kbg ^ (d & 7)) << 3)] = *(bf16x8*)vals;
    }
  }

  __syncthreads();

  const f32x4 zero = {0.f, 0.f, 0.f, 0.f};
  bf16x8 ones;
#pragma unroll
  for (int i = 0; i < 8; i++) ones[i] = (short)0x3F80;  // bf16(1.0)
  u16* pw = Pw[wave];

  bf16x8 qf = *(const bf16x8*)&qkv[(size_t)(node0 + wave * 16 + l16) * 768 + qoff + quad * 8];

#pragma unroll
  for (int qc = 0; qc < 4; qc++) {
    const int q0 = qc * 64 + wave * 16;

    bf16x8 qnext = qf;
    if (qc < 3)
      qnext = *(const bf16x8*)&qkv[(size_t)(node0 + q0 + 64 + l16) * 768 + qoff + quad * 8];

    f32x4 o[2] = {zero, zero};
    f32x4 ls = zero;   // ones-MFMA row-sum accumulator (all regs equal at end)

#pragma unroll
    for (int half = 0; half < 2; half++) {
      f32x4 s[8];
      __builtin_amdgcn_s_setprio(1);
#pragma unroll
      for (int ib = 0; ib < 8; ib++) {
        bf16x8 kf = *(const bf16x8*)&Ks[(half * 128 + ib * 16 + l16) * 32 + quad * 8];
        s[ib] = __builtin_amdgcn_mfma_f32_16x16x32_bf16(kf, qf, zero, 0, 0, 0);
      }
      __builtin_amdgcn_s_setprio(0);

#pragma unroll
      for (int Q = 0; Q < 2; Q++) {
#pragma unroll
        for (int ib = 0; ib < 4; ib++) {
          f32x4 p;
#pragma unroll
          for (int r = 0; r < 4; r++) p[r] = fexp2(s[Q * 4 + ib][r]);
          union { float f; unsigned u; } u0, u1, u2, u3;
          u0.f = p[0]; u1.f = p[1]; u2.f = p[2]; u3.f = p[3];
          uint2 pk;
          pk.x = __builtin_amdgcn_perm(u1.u, u0.u, 0x07060302u);
          pk.y = __builtin_amdgcn_perm(u3.u, u2.u, 0x07060302u);
          const int c = 2 * ib + (quad >> 1);
          *(uint2*)&pw[l16 * 64 + ((c ^ (l16 & 7)) << 3) + (quad & 1) * 4] = pk;
        }
#pragma unroll
        for (int ks = 0; ks < 2; ks++) {
          bf16x8 pf = *(const bf16x8*)&pw[l16 * 64 + (((ks * 4 + quad) ^ (l16 & 7)) << 3)];
          __builtin_amdgcn_s_setprio(1);
#pragma unroll
          for (int ib2 = 0; ib2 < 2; ib2++) {
            const int d = ib2 * 16 + l16;
            const int chunk = half * 16 + Q * 8 + ks * 4 + quad;
            bf16x8 vf = *(const bf16x8*)&Vt[d * 256 + ((chunk ^ (d & 7)) << 3)];
            o[ib2] = __builtin_amdgcn_mfma_f32_16x16x32_bf16(vf, pf, o[ib2], 0, 0, 0);
          }
          ls = __builtin_amdgcn_mfma_f32_16x16x32_bf16(ones, pf, ls, 0, 0, 0);
          __builtin_amdgcn_s_setprio(0);
        }
      }
    }

    const float inv = frcp(ls[0]);   // every lane holds its query's full sum
    const size_t rowbase = (size_t)(node0 + q0 + l16) * 256 + h * 32;
#pragma unroll
    for (int ib2 = 0; ib2 < 2; ib2++) {
      u64 pk = pack4(o[ib2][0] * inv, o[ib2][1] * inv, o[ib2][2] * inv, o[ib2][3] * inv);
      *(u64*)&ob[rowbase + ib2 * 16 + quad * 4] = pk;
    }
    qf = qnext;
  }
}

// ---------------------------------------------------------------------------
// fp32 -> bf16 convert for WEIGHTS only (x is handled by proj_k now).
// Segments: Wp 32768 | in_w 589824 | out_w 196608 | W1 393216 | W2 393216.
// Total 1,605,632 elems = 1568 blocks x 1024 exactly.
// ---------------------------------------------------------------------------
__global__ __launch_bounds__(256) void cvt_k(
    const float* __restrict__ s0, const float* __restrict__ s1,
    const float* __restrict__ s2, const float* __restrict__ s3,
    const float* __restrict__ s4,
    u16* __restrict__ d0, u16* __restrict__ d1, u16* __restrict__ d2,
    u16* __restrict__ d3, u16* __restrict__ d4)
{
  int t = (blockIdx.x * 256 + threadIdx.x) * 4;
  const float* s; u16* d; int off;
  if (t < 32768)        { s = s0; d = d0; off = t; }
  else if (t < 622592)  { s = s1; d = d1; off = t - 32768; }
  else if (t < 819200)  { s = s2; d = d2; off = t - 622592; }
  else if (t < 1212416) { s = s3; d = d3; off = t - 819200; }
  else                  { s = s4; d = d4; off = t - 1212416; }
  float4 v = *(const float4*)(s + off);
  *(u64*)(d + off) = pack4(v.x, v.y, v.z, v.w);
}

extern "C" void kernel_launch(void* const* d_in, const int* in_sizes, int n_in,
                              void* d_out, int out_size, void* d_ws, size_t ws_size,
                              hipStream_t stream) {
  const float* x     = (const float*)d_in[0];
  const float* Wp    = (const float*)d_in[3];
  const float* bp    = (const float*)d_in[4];
  const float* in_w  = (const float*)d_in[5];
  const float* in_b  = (const float*)d_in[6];
  const float* out_w = (const float*)d_in[7];
  const float* out_b = (const float*)d_in[8];
  const float* n1_g  = (const float*)d_in[9];
  const float* n1_b  = (const float*)d_in[10];
  const float* W1    = (const float*)d_in[11];
  const float* b1    = (const float*)d_in[12];
  const float* W2    = (const float*)d_in[13];
  const float* b2    = (const float*)d_in[14];
  const float* n2_g  = (const float*)d_in[15];
  const float* n2_b  = (const float*)d_in[16];
  const float* ln_g  = (const float*)d_in[17];
  const float* ln_b  = (const float*)d_in[18];
  float* out = (float*)d_out;

  if (ws_size < 100000000u) return;  // fail loudly (out stays poisoned)

  char* ws = (char*)d_ws;
  u16* hb  = (u16*)(ws);                        // [32768,256] bf16 residual master
  u16* ob  = (u16*)(ws + 16777216);             // attention out bf16
  u16* mid = (u16*)(ws + 33554432);             // qkv [N,768] / ffn-mid [N,512]
  u16* wb  = (u16*)(ws + 83886080);             // bf16 weights

  u16* Wpb   = wb;
  u16* inwb  = wb + 32768;
  u16* outwb = wb + 622592;
  u16* W1b   = wb + 819200;
  u16* W2b   = wb + 1212416;

  cvt_k<<<1568, 256, 0, stream>>>(Wp, in_w, out_w, W1, W2,
                                  Wpb, inwb, outwb, W1b, W2b);

  // h = x @ Wp^T + bp -> hb (fp32 x consumed directly; converts in-kernel)
  proj_k<<<dim3(2, 256), 256, 0, stream>>>(x, Wpb, bp, hb);

  for (int l = 0; l < 3; l++) {
    // qkv (Q columns pre-scaled by QSCALE for attention)
    gemm_bt<1><<<dim3(6, 256), 256, 0, stream>>>(hb, inwb + l * 196608, in_b + l * 768,
                                                 mid, 768, 256);
    // attention
    attn_k<<<1024, 256, 0, stream>>>(mid, ob);
    // out-proj + residual + LN1 -> hb (bf16, self-referencing res is per-row safe)
    gemm_ln<0, 256><<<512, 256, 0, stream>>>(ob, outwb + l * 65536, out_b + l * 256,
                                             hb, n1_g + l * 256, n1_b + l * 256,
                                             nullptr, nullptr, nullptr, hb);
    // FFN1 (relu) -> mid
    gemm_bt<3><<<dim3(4, 256), 256, 0, stream>>>(hb, W1b + l * 131072, b1 + l * 512,
                                                 mid, 512, 256);
    // FFN2 + residual + LN2 (+final LN on last layer)
    if (l < 2) {
      gemm_ln<0, 512><<<512, 256, 0, stream>>>(mid, W2b + l * 131072, b2 + l * 256,
                                               hb, n2_g + l * 256, n2_b + l * 256,
                                               nullptr, nullptr, nullptr, hb);
    } else {
      gemm_ln<1, 512><<<512, 256, 0, stream>>>(mid, W2b + l * 131072, b2 + l * 256,
                                               hb, n2_g + l * 256, n2_b + l * 256,
                                               ln_g, ln_b, out, nullptr);
    }
  }
}